// Round 3
// baseline (296.437 us; speedup 1.0000x reference)
//
#include <hip/hip_runtime.h>
#include <hip/hip_bf16.h>

#define B_   128
#define T_   512
#define H_   512
#define V_   16
#define OUT_ 64
#define DH_  1024

// LDS: tab float4[V][H] (128K) + tsA float2[T] (4K) + vpk uchar[T] (512B)
#define TAB_BYTES (V_*H_*16)
#define TSA_BYTES (T_*8)
#define VPK_BYTES (T_)
#define SCAN_LDS  (TAB_BYTES + TSA_BYTES + VPK_BYTES)   // 135,680 B

__device__ __forceinline__ float bf2f(unsigned short u) {
    union { unsigned int i; float f; } x; x.i = ((unsigned int)u) << 16; return x.f;
}
__device__ __forceinline__ float sigm(float x) {
    return __builtin_amdgcn_rcpf(1.f + __expf(-x));
}

// ---------------------------------------------------------------------------
// K0: zero s (B*T) + w (B*T) + ctx (B*DH) — 65536 float4s.
// ---------------------------------------------------------------------------
__global__ __launch_bounds__(256) void zero_kernel(float4* __restrict__ p, int n4)
{
    const int i = blockIdx.x * 256 + threadIdx.x;
    if (i < n4) p[i] = make_float4(0.f, 0.f, 0.f, 0.f);
}

// ---------------------------------------------------------------------------
// K1: scan + fused attention-score dot.
// grid (B,2), block 512 (thread = h). Per 8-step group: 1 uint2 (8 v's) +
// 4 float4 ts reads + 8 independent tab b128 reads, then 8 steps of compute.
// Each step also reduces hv*Mu[h] across the wave and atomicAdds into s[b,t].
// ---------------------------------------------------------------------------
__global__ __launch_bounds__(512) void qrnn_scan3(
    const float* __restrict__ x,    // (B,T,3)
    const float* __restrict__ emb,  // (V,10)
    const float* __restrict__ Wf, const float* __restrict__ bf_,
    const float* __restrict__ Wb, const float* __restrict__ bb_,
    const float* __restrict__ Mu,   // (DH,1)
    __hip_bfloat16* __restrict__ hbuf,  // (B,T,DH)
    float* __restrict__ s)          // (B,T) pre-zeroed
{
    const int b = blockIdx.x, dir = blockIdx.y, h = threadIdx.x;
    const int lane = h & 63;
    const float* __restrict__ W    = dir ? Wb  : Wf;
    const float* __restrict__ bias = dir ? bb_ : bf_;

    extern __shared__ char smem[];
    float4*        tab = (float4*)smem;                       // [V][H]
    float2*        tsA = (float2*)(smem + TAB_BYTES);         // [T]
    unsigned char* vpk = (unsigned char*)(smem + TAB_BYTES + TSA_BYTES); // [T]

    {   // stage x: one thread per t
        const int t = h;
        const float* xp = x + ((size_t)b*T_ + t)*3;
        tsA[t] = make_float2(xp[0], xp[1]);
        vpk[t] = (unsigned char)(int)xp[2];
    }

    // per-thread weight columns for ts0/ts1 rows + emb rows
    float w0[3], w1[3], wt[10][3];
#pragma unroll
    for (int g = 0; g < 3; ++g) {
        w0[g] = W[g*H_ + h];
        w1[g] = W[1536 + g*H_ + h];
#pragma unroll
        for (int e = 0; e < 10; ++e)
            wt[e][g] = W[(2+e)*1536 + g*H_ + h];
    }
    const float bz = bias[h], bfv = bias[H_+h], bov = bias[2*H_+h];

    // gate table tab[v] = bias + emb[v] . W[2:12]
#pragma unroll
    for (int v = 0; v < V_; ++v) {
        float a0 = bz, a1 = bfv, a2 = bov;
#pragma unroll
        for (int e = 0; e < 10; ++e) {
            const float ev = emb[v*10 + e];
            a0 = fmaf(ev, wt[e][0], a0);
            a1 = fmaf(ev, wt[e][1], a1);
            a2 = fmaf(ev, wt[e][2], a2);
        }
        tab[v*H_ + h] = make_float4(a0, a1, a2, 0.f);
    }
    const float mu = Mu[dir*H_ + h];
    __syncthreads();

    const float4* tsA4 = (const float4*)tsA;   // 2 steps per float4
    const uint2*  vp2  = (const uint2*)vpk;    // 8 steps per uint2

    float c = 0.f;
    __hip_bfloat16* hb = hbuf + (size_t)b*T_*DH_ + dir*H_ + h;
    float* sb = s + b*T_;

#define STEP(i, TS0, TS1, G) { \
    const int t = t0 + (i); \
    float zp = fmaf(TS0, w0[0], fmaf(TS1, w1[0], (G).x)); \
    float fp = fmaf(TS0, w0[1], fmaf(TS1, w1[1], (G).y)); \
    float op = fmaf(TS0, w0[2], fmaf(TS1, w1[2], (G).z)); \
    const float f = sigm(fp); \
    const float o = sigm(op); \
    const float z = fmaf(2.f, sigm(2.f*zp), -1.f); \
    c = fmaf(f, c - z, z); \
    const float hv = fmaxf(o * c, 0.f); \
    hb[(size_t)t*DH_] = __float2bfloat16(hv); \
    float red = hv * mu; \
    red += __shfl_xor(red, 1); \
    red += __shfl_xor(red, 2); \
    red += __shfl_xor(red, 4); \
    red += __shfl_xor(red, 8); \
    red += __shfl_xor(red, 16); \
    red += __shfl_xor(red, 32); \
    if (lane == 0) atomicAdd(&sb[t], red); \
}

#pragma unroll 2
    for (int gi = 0; gi < T_/8; ++gi) {
        const int gg = dir ? (T_/8 - 1 - gi) : gi;
        const int t0 = gg*8;
        const uint2  vp  = vp2[gg];
        const float4 tsa = tsA4[gg*4 + 0];
        const float4 tsb = tsA4[gg*4 + 1];
        const float4 tsc = tsA4[gg*4 + 2];
        const float4 tsd = tsA4[gg*4 + 3];
        const int v0 =  vp.x        & 255, v1 = (vp.x >> 8) & 255;
        const int v2 = (vp.x >> 16) & 255, v3 =  vp.x >> 24;
        const int v4 =  vp.y        & 255, v5 = (vp.y >> 8) & 255;
        const int v6 = (vp.y >> 16) & 255, v7 =  vp.y >> 24;
        const float4 g0 = tab[v0*H_ + h];
        const float4 g1 = tab[v1*H_ + h];
        const float4 g2 = tab[v2*H_ + h];
        const float4 g3 = tab[v3*H_ + h];
        const float4 g4 = tab[v4*H_ + h];
        const float4 g5 = tab[v5*H_ + h];
        const float4 g6 = tab[v6*H_ + h];
        const float4 g7 = tab[v7*H_ + h];
        if (dir == 0) {
            STEP(0, tsa.x, tsa.y, g0) STEP(1, tsa.z, tsa.w, g1)
            STEP(2, tsb.x, tsb.y, g2) STEP(3, tsb.z, tsb.w, g3)
            STEP(4, tsc.x, tsc.y, g4) STEP(5, tsc.z, tsc.w, g5)
            STEP(6, tsd.x, tsd.y, g6) STEP(7, tsd.z, tsd.w, g7)
        } else {
            STEP(7, tsd.z, tsd.w, g7) STEP(6, tsd.x, tsd.y, g6)
            STEP(5, tsc.z, tsc.w, g5) STEP(4, tsc.x, tsc.y, g4)
            STEP(3, tsb.z, tsb.w, g3) STEP(2, tsb.x, tsb.y, g2)
            STEP(1, tsa.z, tsa.w, g1) STEP(0, tsa.x, tsa.y, g0)
        }
    }
#undef STEP
}

// ---------------------------------------------------------------------------
// K3: softmax over t per batch (s already holds the full dot). grid B, 512.
// ---------------------------------------------------------------------------
__global__ __launch_bounds__(512) void softmax_kernel(
    const float* __restrict__ s, float* __restrict__ w)
{
    const int b = blockIdx.x;
    const int t = threadIdx.x;
    const float v = s[b*T_ + t];

    __shared__ float redm[8];
    __shared__ float reds[8];

    float m = v;
#pragma unroll
    for (int off = 32; off; off >>= 1) m = fmaxf(m, __shfl_xor(m, off));
    if ((t & 63) == 0) redm[t >> 6] = m;
    __syncthreads();
    float mall = redm[0];
#pragma unroll
    for (int i = 1; i < 8; ++i) mall = fmaxf(mall, redm[i]);

    const float e = __expf(v - mall);
    float sum = e;
#pragma unroll
    for (int off = 32; off; off >>= 1) sum += __shfl_xor(sum, off);
    if ((t & 63) == 0) reds[t >> 6] = sum;
    __syncthreads();
    float sall = 0.f;
#pragma unroll
    for (int i = 0; i < 8; ++i) sall += reds[i];

    w[b*T_ + t] = e / sall;
}

// ---------------------------------------------------------------------------
// K4: context partial over a T-chunk; accumulate into zeroed ctx via atomics.
// grid (B,8), block 256; thread owns 4 d's (uint2 = 4 bf16 per t).
// ---------------------------------------------------------------------------
__global__ __launch_bounds__(256) void context3(
    const __hip_bfloat16* __restrict__ hbuf, const float* __restrict__ w,
    float* __restrict__ ctx)
{
    const int b = blockIdx.x, q = blockIdx.y;
    const int d0 = threadIdx.x * 4;

    __shared__ float ws[64];
    if (threadIdx.x < 64) ws[threadIdx.x] = w[b*T_ + q*64 + threadIdx.x];
    __syncthreads();

    const char* hp = (const char*)(hbuf + ((size_t)b*T_ + q*64)*DH_ + d0);
    float a0 = 0.f, a1 = 0.f, a2 = 0.f, a3 = 0.f;
#pragma unroll 8
    for (int i = 0; i < 64; ++i) {
        const uint2 u = *(const uint2*)(hp + (size_t)i*(DH_*2));
        const float wv = ws[i];
        a0 = fmaf(bf2f((unsigned short)(u.x & 0xffffu)), wv, a0);
        a1 = fmaf(bf2f((unsigned short)(u.x >> 16)),     wv, a1);
        a2 = fmaf(bf2f((unsigned short)(u.y & 0xffffu)), wv, a2);
        a3 = fmaf(bf2f((unsigned short)(u.y >> 16)),     wv, a3);
    }
    float* cp = ctx + b*DH_ + d0;
    atomicAdd(cp + 0, a0);
    atomicAdd(cp + 1, a1);
    atomicAdd(cp + 2, a2);
    atomicAdd(cp + 3, a3);
}

// ---------------------------------------------------------------------------
// K5: out[b,o] = dot(relu(ctx[b,:]), W_out[o,:]) + b_out[o]. One wave per (b,o).
// ---------------------------------------------------------------------------
__global__ __launch_bounds__(256) void out_kernel(
    const float* __restrict__ ctx, const float* __restrict__ Wout,
    const float* __restrict__ bout, float* __restrict__ out)
{
    const int idx  = blockIdx.x*4 + (threadIdx.x >> 6);  // b*64 + o
    const int lane = threadIdx.x & 63;
    const int b = idx >> 6;
    const int o = idx & 63;
    const float* cp = ctx + b*DH_;
    const float* wp = Wout + o*DH_;
    float acc = 0.f;
#pragma unroll
    for (int k = 0; k < DH_/64; ++k) {
        const int d = lane + k*64;
        acc = fmaf(fmaxf(cp[d], 0.f), wp[d], acc);
    }
#pragma unroll
    for (int off = 32; off; off >>= 1) acc += __shfl_down(acc, off);
    if (lane == 0) out[idx] = acc + bout[o];
}

// ---------------------------------------------------------------------------
extern "C" void kernel_launch(void* const* d_in, const int* in_sizes, int n_in,
                              void* d_out, int out_size, void* d_ws, size_t ws_size,
                              hipStream_t stream)
{
    const float* x    = (const float*)d_in[0];
    const float* emb  = (const float*)d_in[1];
    const float* Wf   = (const float*)d_in[2];
    const float* bf_  = (const float*)d_in[3];
    const float* Wb   = (const float*)d_in[4];
    const float* bb_  = (const float*)d_in[5];
    const float* Mu   = (const float*)d_in[6];
    const float* Wout = (const float*)d_in[7];
    const float* bout = (const float*)d_in[8];
    float* out = (float*)d_out;

    char* ws = (char*)d_ws;
    const size_t hbytes = (size_t)B_*T_*DH_*sizeof(__hip_bfloat16);  // 134.2 MB
    __hip_bfloat16* hbuf = (__hip_bfloat16*)ws;
    float* s   = (float*)(ws + hbytes);   // B*T
    float* w   = s + B_*T_;               // B*T
    float* ctx = w + B_*T_;               // B*DH
    // total footprint: 134.2 MB + 1 MB tail (same as round 2's proven layout)

    (void)hipFuncSetAttribute((const void*)qrnn_scan3,
                              hipFuncAttributeMaxDynamicSharedMemorySize,
                              SCAN_LDS);

    // zero s + w + ctx (contiguous): (2*B*T + B*DH) floats = 65536 float4
    const int n4 = (2*B_*T_ + B_*DH_) / 4;
    zero_kernel<<<(n4 + 255)/256, 256, 0, stream>>>((float4*)s, n4);

    qrnn_scan3<<<dim3(B_, 2), 512, SCAN_LDS, stream>>>(x, emb, Wf, bf_, Wb, bb_,
                                                       Mu, hbuf, s);
    softmax_kernel<<<B_, 512, 0, stream>>>(s, w);
    context3<<<dim3(B_, 8), 256, 0, stream>>>(hbuf, w, ctx);
    out_kernel<<<(B_*OUT_)/4, 256, 0, stream>>>(ctx, Wout, bout, out);
}

// Round 4
// 193.907 us; speedup vs baseline: 1.5288x; 1.5288x over previous
//
#include <hip/hip_runtime.h>
#include <hip/hip_bf16.h>

#define B_   128
#define T_   512
#define H_   512
#define V_   16
#define OUT_ 64
#define DH_  1024

// LDS: tab float4[V][H] (128K) + tsA float2[T] (4K) + vpk uchar[T] (512B)
#define TAB_BYTES (V_*H_*16)
#define TSA_BYTES (T_*8)
#define VPK_BYTES (T_)
#define SCAN_LDS  (TAB_BYTES + TSA_BYTES + VPK_BYTES)   // 135,680 B

__device__ __forceinline__ float bf2f(unsigned short u) {
    union { unsigned int i; float f; } x; x.i = ((unsigned int)u) << 16; return x.f;
}

// ---------------------------------------------------------------------------
// K0: zero ctx (B*DH floats = 32768 float4)
// ---------------------------------------------------------------------------
__global__ __launch_bounds__(256) void zero_kernel(float4* __restrict__ p, int n4)
{
    const int i = blockIdx.x * 256 + threadIdx.x;
    if (i < n4) p[i] = make_float4(0.f, 0.f, 0.f, 0.f);
}

// ---------------------------------------------------------------------------
// K1: bidirectional QRNN scan. grid (B,2), block 512 (thread = h).
// Per 8-step group: 1 uint2 (8 v's) + 4 float4 ts reads + 8 INDEPENDENT
// tab b128 reads (latencies overlap), then 8 steps of pure register compute.
// log2e factors folded into table + ts-weights: sigmoid = rcp(1+exp2(pre)).
// ---------------------------------------------------------------------------
__global__ __launch_bounds__(512) void qrnn_scan4(
    const float* __restrict__ x,    // (B,T,3)
    const float* __restrict__ emb,  // (V,10)
    const float* __restrict__ Wf, const float* __restrict__ bf_,
    const float* __restrict__ Wb, const float* __restrict__ bb_,
    __hip_bfloat16* __restrict__ hbuf)  // (B,T,DH)
{
    const int b = blockIdx.x, dir = blockIdx.y, h = threadIdx.x;
    const float* __restrict__ W    = dir ? Wb  : Wf;
    const float* __restrict__ bias = dir ? bb_ : bf_;

    extern __shared__ char smem[];
    float4*        tab = (float4*)smem;                       // [V][H]
    float2*        tsA = (float2*)(smem + TAB_BYTES);         // [T]
    unsigned char* vpk = (unsigned char*)(smem + TAB_BYTES + TSA_BYTES); // [T]

    {   // stage x: one thread per t
        const int t = h;
        const float* xp = x + ((size_t)b*T_ + t)*3;
        tsA[t] = make_float2(xp[0], xp[1]);
        vpk[t] = (unsigned char)(int)xp[2];
    }

    // per-thread weight columns
    float w0[3], w1[3], wt[10][3];
#pragma unroll
    for (int g = 0; g < 3; ++g) {
        w0[g] = W[g*H_ + h];
        w1[g] = W[1536 + g*H_ + h];
#pragma unroll
        for (int e = 0; e < 10; ++e)
            wt[e][g] = W[(2+e)*1536 + g*H_ + h];
    }
    const float bz = bias[h], bfv = bias[H_+h], bov = bias[2*H_+h];

    const float FZ = -2.8853900817779268f;   // -2*log2(e)  (z gate / tanh)
    const float FF = -1.4426950408889634f;   // -log2(e)    (f,o gates)

    // gate table tab[v] = scale * (bias + emb[v] . W[2:12])
#pragma unroll
    for (int v = 0; v < V_; ++v) {
        float a0 = bz, a1 = bfv, a2 = bov;
#pragma unroll
        for (int e = 0; e < 10; ++e) {
            const float ev = emb[v*10 + e];   // uniform -> scalar load
            a0 = fmaf(ev, wt[e][0], a0);
            a1 = fmaf(ev, wt[e][1], a1);
            a2 = fmaf(ev, wt[e][2], a2);
        }
        tab[v*H_ + h] = make_float4(FZ*a0, FF*a1, FF*a2, 0.f);
    }
    // scaled per-step weights
    const float w0z = FZ*w0[0], w0f = FF*w0[1], w0o = FF*w0[2];
    const float w1z = FZ*w1[0], w1f = FF*w1[1], w1o = FF*w1[2];
    __syncthreads();

    const float4* tsA4 = (const float4*)tsA;   // 2 steps per float4
    const uint2*  vp2  = (const uint2*)vpk;    // 8 steps per uint2

    float c = 0.f;
    __hip_bfloat16* hb = hbuf + (size_t)b*T_*DH_ + dir*H_ + h;

#define STEP(i, TS0, TS1, G) { \
    const int t = t0 + (i); \
    const float zp = fmaf(TS0, w0z, fmaf(TS1, w1z, (G).x)); \
    const float fp = fmaf(TS0, w0f, fmaf(TS1, w1f, (G).y)); \
    const float op = fmaf(TS0, w0o, fmaf(TS1, w1o, (G).z)); \
    const float rz = __builtin_amdgcn_rcpf(1.f + __builtin_amdgcn_exp2f(zp)); \
    const float f  = __builtin_amdgcn_rcpf(1.f + __builtin_amdgcn_exp2f(fp)); \
    const float o  = __builtin_amdgcn_rcpf(1.f + __builtin_amdgcn_exp2f(op)); \
    const float z  = fmaf(2.f, rz, -1.f); \
    c = fmaf(f, c - z, z); \
    const float hv = fmaxf(o * c, 0.f); \
    hb[(size_t)t*DH_] = __float2bfloat16(hv); \
}

#pragma unroll 2
    for (int gi = 0; gi < T_/8; ++gi) {
        const int gg = dir ? (T_/8 - 1 - gi) : gi;
        const int t0 = gg*8;
        const uint2  vp  = vp2[gg];
        const float4 tsa = tsA4[gg*4 + 0];
        const float4 tsb = tsA4[gg*4 + 1];
        const float4 tsc = tsA4[gg*4 + 2];
        const float4 tsd = tsA4[gg*4 + 3];
        const int v0 =  vp.x        & 255, v1 = (vp.x >> 8) & 255;
        const int v2 = (vp.x >> 16) & 255, v3 =  vp.x >> 24;
        const int v4 =  vp.y        & 255, v5 = (vp.y >> 8) & 255;
        const int v6 = (vp.y >> 16) & 255, v7 =  vp.y >> 24;
        const float4 g0 = tab[v0*H_ + h];
        const float4 g1 = tab[v1*H_ + h];
        const float4 g2 = tab[v2*H_ + h];
        const float4 g3 = tab[v3*H_ + h];
        const float4 g4 = tab[v4*H_ + h];
        const float4 g5 = tab[v5*H_ + h];
        const float4 g6 = tab[v6*H_ + h];
        const float4 g7 = tab[v7*H_ + h];
        if (dir == 0) {
            STEP(0, tsa.x, tsa.y, g0) STEP(1, tsa.z, tsa.w, g1)
            STEP(2, tsb.x, tsb.y, g2) STEP(3, tsb.z, tsb.w, g3)
            STEP(4, tsc.x, tsc.y, g4) STEP(5, tsc.z, tsc.w, g5)
            STEP(6, tsd.x, tsd.y, g6) STEP(7, tsd.z, tsd.w, g7)
        } else {
            STEP(7, tsd.z, tsd.w, g7) STEP(6, tsd.x, tsd.y, g6)
            STEP(5, tsc.z, tsc.w, g5) STEP(4, tsc.x, tsc.y, g4)
            STEP(3, tsb.z, tsb.w, g3) STEP(2, tsb.x, tsb.y, g2)
            STEP(1, tsa.z, tsa.w, g1) STEP(0, tsa.x, tsa.y, g0)
        }
    }
#undef STEP
}

// ---------------------------------------------------------------------------
// K2: s[b,t] = dot(hbuf[b,t,:], Mu). One wave per row, 16 bf16/lane.
// ---------------------------------------------------------------------------
__global__ __launch_bounds__(256) void score2(
    const __hip_bfloat16* __restrict__ hbuf, const float* __restrict__ Mu,
    float* __restrict__ s)
{
    const int row  = blockIdx.x*4 + (threadIdx.x >> 6);
    const int lane = threadIdx.x & 63;
    const uint4* hp = (const uint4*)(hbuf + (size_t)row*DH_);
    const float4* mp = (const float4*)Mu;
    float acc = 0.f;
#pragma unroll
    for (int k = 0; k < 2; ++k) {
        const int idx = k*64 + lane;
        const uint4 hv = hp[idx];            // 16B coalesced = 8 bf16
        const float4 m0 = mp[idx*2];
        const float4 m1 = mp[idx*2 + 1];
        acc = fmaf(bf2f((unsigned short)(hv.x & 0xffffu)), m0.x, acc);
        acc = fmaf(bf2f((unsigned short)(hv.x >> 16)),     m0.y, acc);
        acc = fmaf(bf2f((unsigned short)(hv.y & 0xffffu)), m0.z, acc);
        acc = fmaf(bf2f((unsigned short)(hv.y >> 16)),     m0.w, acc);
        acc = fmaf(bf2f((unsigned short)(hv.z & 0xffffu)), m1.x, acc);
        acc = fmaf(bf2f((unsigned short)(hv.z >> 16)),     m1.y, acc);
        acc = fmaf(bf2f((unsigned short)(hv.w & 0xffffu)), m1.z, acc);
        acc = fmaf(bf2f((unsigned short)(hv.w >> 16)),     m1.w, acc);
    }
#pragma unroll
    for (int off = 32; off; off >>= 1) acc += __shfl_down(acc, off);
    if (lane == 0) s[row] = acc;
}

// ---------------------------------------------------------------------------
// K3: softmax over t per batch. grid B, block 512.
// ---------------------------------------------------------------------------
__global__ __launch_bounds__(512) void softmax_kernel(
    const float* __restrict__ s, float* __restrict__ w)
{
    const int b = blockIdx.x;
    const int t = threadIdx.x;
    const float v = s[b*T_ + t];

    __shared__ float redm[8];
    __shared__ float reds[8];

    float m = v;
#pragma unroll
    for (int off = 32; off; off >>= 1) m = fmaxf(m, __shfl_xor(m, off));
    if ((t & 63) == 0) redm[t >> 6] = m;
    __syncthreads();
    float mall = redm[0];
#pragma unroll
    for (int i = 1; i < 8; ++i) mall = fmaxf(mall, redm[i]);

    const float e = __expf(v - mall);
    float sum = e;
#pragma unroll
    for (int off = 32; off; off >>= 1) sum += __shfl_xor(sum, off);
    if ((t & 63) == 0) reds[t >> 6] = sum;
    __syncthreads();
    float sall = 0.f;
#pragma unroll
    for (int i = 0; i < 8; ++i) sall += reds[i];

    w[b*T_ + t] = e / sall;
}

// ---------------------------------------------------------------------------
// K4: context partial over a T-chunk; accumulate into zeroed ctx via atomics.
// grid (B,8), block 256; thread owns 4 d's (uint2 = 4 bf16 per t).
// ---------------------------------------------------------------------------
__global__ __launch_bounds__(256) void context3(
    const __hip_bfloat16* __restrict__ hbuf, const float* __restrict__ w,
    float* __restrict__ ctx)
{
    const int b = blockIdx.x, q = blockIdx.y;
    const int d0 = threadIdx.x * 4;

    __shared__ float ws[64];
    if (threadIdx.x < 64) ws[threadIdx.x] = w[b*T_ + q*64 + threadIdx.x];
    __syncthreads();

    const char* hp = (const char*)(hbuf + ((size_t)b*T_ + q*64)*DH_ + d0);
    float a0 = 0.f, a1 = 0.f, a2 = 0.f, a3 = 0.f;
#pragma unroll 8
    for (int i = 0; i < 64; ++i) {
        const uint2 u = *(const uint2*)(hp + (size_t)i*(DH_*2));
        const float wv = ws[i];
        a0 = fmaf(bf2f((unsigned short)(u.x & 0xffffu)), wv, a0);
        a1 = fmaf(bf2f((unsigned short)(u.x >> 16)),     wv, a1);
        a2 = fmaf(bf2f((unsigned short)(u.y & 0xffffu)), wv, a2);
        a3 = fmaf(bf2f((unsigned short)(u.y >> 16)),     wv, a3);
    }
    float* cp = ctx + b*DH_ + d0;
    atomicAdd(cp + 0, a0);
    atomicAdd(cp + 1, a1);
    atomicAdd(cp + 2, a2);
    atomicAdd(cp + 3, a3);
}

// ---------------------------------------------------------------------------
// K5: out[b,o] = dot(relu(ctx[b,:]), W_out[o,:]) + b_out[o]. One wave per (b,o).
// ---------------------------------------------------------------------------
__global__ __launch_bounds__(256) void out_kernel(
    const float* __restrict__ ctx, const float* __restrict__ Wout,
    const float* __restrict__ bout, float* __restrict__ out)
{
    const int idx  = blockIdx.x*4 + (threadIdx.x >> 6);  // b*64 + o
    const int lane = threadIdx.x & 63;
    const int b = idx >> 6;
    const int o = idx & 63;
    const float* cp = ctx + b*DH_;
    const float* wp = Wout + o*DH_;
    float acc = 0.f;
#pragma unroll
    for (int k = 0; k < DH_/64; ++k) {
        const int d = lane + k*64;
        acc = fmaf(fmaxf(cp[d], 0.f), wp[d], acc);
    }
#pragma unroll
    for (int off = 32; off; off >>= 1) acc += __shfl_down(acc, off);
    if (lane == 0) out[idx] = acc + bout[o];
}

// ---------------------------------------------------------------------------
extern "C" void kernel_launch(void* const* d_in, const int* in_sizes, int n_in,
                              void* d_out, int out_size, void* d_ws, size_t ws_size,
                              hipStream_t stream)
{
    const float* x    = (const float*)d_in[0];
    const float* emb  = (const float*)d_in[1];
    const float* Wf   = (const float*)d_in[2];
    const float* bf_  = (const float*)d_in[3];
    const float* Wb   = (const float*)d_in[4];
    const float* bb_  = (const float*)d_in[5];
    const float* Mu   = (const float*)d_in[6];
    const float* Wout = (const float*)d_in[7];
    const float* bout = (const float*)d_in[8];
    float* out = (float*)d_out;

    char* ws = (char*)d_ws;
    const size_t hbytes = (size_t)B_*T_*DH_*sizeof(__hip_bfloat16);  // 134.2 MB
    __hip_bfloat16* hbuf = (__hip_bfloat16*)ws;
    float* s   = (float*)(ws + hbytes);   // B*T
    float* w   = s + B_*T_;               // B*T
    float* ctx = w + B_*T_;               // B*DH

    (void)hipFuncSetAttribute((const void*)qrnn_scan4,
                              hipFuncAttributeMaxDynamicSharedMemorySize,
                              SCAN_LDS);

    // zero only ctx (atomically accumulated)
    const int n4 = (B_*DH_) / 4;
    zero_kernel<<<(n4 + 255)/256, 256, 0, stream>>>((float4*)ctx, n4);

    qrnn_scan4<<<dim3(B_, 2), 512, SCAN_LDS, stream>>>(x, emb, Wf, bf_, Wb, bb_, hbuf);
    score2<<<(B_*T_)/4, 256, 0, stream>>>(hbuf, Mu, s);
    softmax_kernel<<<B_, 512, 0, stream>>>(s, w);
    context3<<<dim3(B_, 8), 256, 0, stream>>>(hbuf, w, ctx);
    out_kernel<<<(B_*OUT_)/4, 256, 0, stream>>>(ctx, Wout, bout, out);
}